// Round 1
// baseline (121.363 us; speedup 1.0000x reference)
//
#include <hip/hip_runtime.h>

// PHM embedding: out[t, q*256+j] = sum_k a[k, p, q] * s[k, i, j]
//   v = input[t], p = v / 12565, i = v % 12565.
// VOCAB=50257, EMB=1024, PHM=4 -> NROW=12565.
// Inputs: input int32[16384], a f32[64], s f32[4*12565*256]. Output f32[16384*1024].
//
// R4 = R3 + pinned full occupancy:
// __launch_bounds__(256, 8) forces VGPR <= 64 so every SIMD holds 8 waves
// (32 waves/CU) and the 2048-block grid runs as exactly one full dispatch
// round (8 blocks/CU x 256 CUs). Without the second arg the allocator is
// free to exceed 64 VGPRs, which would drop to 7 blocks/CU and add a
// partial tail round. Kernel is mixed-stream HBM-bound:
//   write 67 MB (nontemporal, streaming) + ~37 MB compulsory s fetch
//   (repeat reads hit the 256 MiB L3, since s = 51.5 MB is L3-resident).
// One wave per TPW=2 tokens; all 8 gathered v4f loads issued before any
// use; s-row vectors reused in regs for all 4 output quarters.

typedef float v4f __attribute__((ext_vector_type(4)));

#define NROW 12565
#define NTOK (8 * 2048)
#define TPW 2                      // tokens per wave
#define NBLK (NTOK / (4 * TPW))    // 2048 blocks

__global__ __launch_bounds__(256, 8) void phm_embed_kernel(
    const int* __restrict__ idx,
    const float* __restrict__ a,
    const float* __restrict__ s,
    float* __restrict__ out)
{
    __shared__ float a_sh[64];
    const int tid = threadIdx.x;
    if (tid < 64) a_sh[tid] = a[tid];
    __syncthreads();

    const size_t KSTR = (size_t)NROW * 256;   // k-plane stride in s
    const int wave = blockIdx.x * 4 + (tid >> 6);
    const int lane = tid & 63;
    const int j0 = lane << 2;                 // 4 consecutive floats per lane
    const int t0 = wave * TPW;

    const int tA = t0;
    const int tB = t0 + 1;
    const int vA = __builtin_nontemporal_load(idx + tA);  // wave-uniform, no reuse
    const int vB = __builtin_nontemporal_load(idx + tB);
    const int pA = vA / NROW;  const int iA = vA - pA * NROW;
    const int pB = vB / NROW;  const int iB = vB - pB * NROW;

    const float* sA = s + (size_t)iA * 256 + j0;
    const float* sB = s + (size_t)iB * 256 + j0;

    // issue all 8 loads (8 KiB/wave in flight) before any use
    const v4f A0 = *(const v4f*)(sA + 0 * KSTR);
    const v4f A1 = *(const v4f*)(sA + 1 * KSTR);
    const v4f A2 = *(const v4f*)(sA + 2 * KSTR);
    const v4f A3 = *(const v4f*)(sA + 3 * KSTR);
    const v4f B0 = *(const v4f*)(sB + 0 * KSTR);
    const v4f B1 = *(const v4f*)(sB + 1 * KSTR);
    const v4f B2 = *(const v4f*)(sB + 2 * KSTR);
    const v4f B3 = *(const v4f*)(sB + 3 * KSTR);

    v4f* oA = (v4f*)(out + (size_t)tA * 1024 + j0);
    v4f* oB = (v4f*)(out + (size_t)tB * 1024 + j0);

    #pragma unroll
    for (int q = 0; q < 4; ++q) {
        const float c0 = a_sh[0 * 16 + pA * 4 + q];
        const float c1 = a_sh[1 * 16 + pA * 4 + q];
        const float c2 = a_sh[2 * 16 + pA * 4 + q];
        const float c3 = a_sh[3 * 16 + pA * 4 + q];
        v4f o = c0 * A0 + c1 * A1 + c2 * A2 + c3 * A3;
        __builtin_nontemporal_store(o, oA + q * 64);   // q*256 floats = q*64 v4f
    }
    #pragma unroll
    for (int q = 0; q < 4; ++q) {
        const float c0 = a_sh[0 * 16 + pB * 4 + q];
        const float c1 = a_sh[1 * 16 + pB * 4 + q];
        const float c2 = a_sh[2 * 16 + pB * 4 + q];
        const float c3 = a_sh[3 * 16 + pB * 4 + q];
        v4f o = c0 * B0 + c1 * B1 + c2 * B2 + c3 * B3;
        __builtin_nontemporal_store(o, oB + q * 64);
    }
}

extern "C" void kernel_launch(void* const* d_in, const int* in_sizes, int n_in,
                              void* d_out, int out_size, void* d_ws, size_t ws_size,
                              hipStream_t stream) {
    const int*   idx = (const int*)d_in[0];
    const float* a   = (const float*)d_in[1];
    const float* s   = (const float*)d_in[2];
    float*       out = (float*)d_out;

    phm_embed_kernel<<<NBLK, 256, 0, stream>>>(idx, a, s, out);
}

// Round 2
// 111.179 us; speedup vs baseline: 1.0916x; 1.0916x over previous
//
#include <hip/hip_runtime.h>

// PHM embedding: out[t, q*256+j] = sum_k a[k, p, q] * s[k, i, j]
//   v = input[t], p = v / 12565, i = v % 12565.
// VOCAB=50257, EMB=1024, PHM=4 -> NROW=12565.
// Inputs: input int32[16384], a f32[64], s f32[4*12565*256]. Output f32[16384*1024].
//
// R5 = R3 reverted (R4's forced __launch_bounds__(256,8) regressed ~9us:
// squeezing to <=64 VGPR serialized the in-flight gather loads), with the
// occupancy goal achieved STRUCTURALLY instead: TPW=1 -> one token per wave,
// 4 x v4f = 16 VGPRs of live gather data, so the allocator lands <=64 VGPR
// naturally. 4096 blocks x 256 thr; aggregate in-flight bytes unchanged
// (2x waves x half the loads each), per-token ILP intact (all 4 k-plane
// loads issued before any use), TLP doubled.
// Kernel is mixed-stream HBM-bound: ~37.5 MB compulsory s fetch (repeat
// reads hit the 256 MiB L3; s = 51.5 MB is L3-resident) + 67 MB
// nontemporal streaming write.

typedef float v4f __attribute__((ext_vector_type(4)));

#define NROW 12565
#define NTOK (8 * 2048)
#define NBLK (NTOK / 4)            // 1 token per wave, 4 waves per block

__global__ __launch_bounds__(256) void phm_embed_kernel(
    const int* __restrict__ idx,
    const float* __restrict__ a,
    const float* __restrict__ s,
    float* __restrict__ out)
{
    __shared__ float a_sh[64];
    const int tid = threadIdx.x;
    if (tid < 64) a_sh[tid] = a[tid];
    __syncthreads();

    const size_t KSTR = (size_t)NROW * 256;   // k-plane stride in s
    const int t = blockIdx.x * 4 + (tid >> 6);  // token = global wave id
    const int lane = tid & 63;
    const int j0 = lane << 2;                 // 4 consecutive floats per lane

    const int v = idx[t];                     // wave-uniform
    const int p = v / NROW;
    const int i = v - p * NROW;

    const float* sp = s + (size_t)i * 256 + j0;

    // issue all 4 k-plane loads (4 KiB/wave in flight) before any use
    const v4f S0 = *(const v4f*)(sp + 0 * KSTR);
    const v4f S1 = *(const v4f*)(sp + 1 * KSTR);
    const v4f S2 = *(const v4f*)(sp + 2 * KSTR);
    const v4f S3 = *(const v4f*)(sp + 3 * KSTR);

    v4f* o = (v4f*)(out + (size_t)t * 1024 + j0);

    #pragma unroll
    for (int q = 0; q < 4; ++q) {
        const float c0 = a_sh[0 * 16 + p * 4 + q];
        const float c1 = a_sh[1 * 16 + p * 4 + q];
        const float c2 = a_sh[2 * 16 + p * 4 + q];
        const float c3 = a_sh[3 * 16 + p * 4 + q];
        v4f r = c0 * S0 + c1 * S1 + c2 * S2 + c3 * S3;
        __builtin_nontemporal_store(r, o + q * 64);   // q*256 floats = q*64 v4f
    }
}

extern "C" void kernel_launch(void* const* d_in, const int* in_sizes, int n_in,
                              void* d_out, int out_size, void* d_ws, size_t ws_size,
                              hipStream_t stream) {
    const int*   idx = (const int*)d_in[0];
    const float* a   = (const float*)d_in[1];
    const float* s   = (const float*)d_in[2];
    float*       out = (float*)d_out;

    phm_embed_kernel<<<NBLK, 256, 0, stream>>>(idx, a, s, out);
}